// Round 10
// baseline (150.752 us; speedup 1.0000x reference)
//
#include <hip/hip_runtime.h>
#include <hip/hip_bf16.h>

#define N_NODES   100000
#define N_EDGES   1250000
#define N_GRAPHS  512
#define HIDDEN    64
#define F_IN      3
#define N_CLASSES 5

// bucket sort parameters
#define BKT_SHIFT 8
#define BKT_NODES 256                                      // nodes per bucket
#define N_BKT     ((N_NODES + BKT_NODES - 1) / BKT_NODES)  // 391
#define CAP       4096                                     // fixed bucket capacity
// ROUND-9: EBLK 512 -> 1024 (k_scat was at 50% thread occupancy; scat is a
// latency-chain kernel and needs the full 2048 thr/CU). ECHUNK rounded to
// EVEN so per-block edge ranges stay 8B-aligned for int2 reads.
#define EBLK      1024
#define ECHUNK    ((((N_EDGES + EBLK - 1) / EBLK) + 1) & ~1)   // 1222
#define SCT       512                                      // k_scat threads
#define NREP      8                                        // gsum replicas

// bf16 helpers (RNE; inputs are finite)
__device__ __forceinline__ unsigned short f2bf(float f) {
    unsigned u = __float_as_uint(f);
    u += 0x7FFF + ((u >> 16) & 1);
    return (unsigned short)(u >> 16);
}

// ---------------------------------------------------------------------------
// k_scat: merged hist + scan + bucket-base claim + LDS counting-sort reorder
// + bucket-contiguous write-out (+ head fold, gstart in extra blocks).
// R8-proven structure; R9 adds 2x blocks (full occupancy) + int2 edge reads.
__global__ void k_scat(const int* __restrict__ src, const int* __restrict__ dst,
                       const float* __restrict__ W2, const float* __restrict__ Wl,
                       const float* __restrict__ b2, const float* __restrict__ bl,
                       const int* __restrict__ batch,
                       int* __restrict__ gcur, int* __restrict__ ebuf,
                       float* __restrict__ Wc, float* __restrict__ bc,
                       int* __restrict__ gstart) {
    int b = blockIdx.x;
    int tid = threadIdx.x;
    if (b >= EBLK) {
        int bb = b - EBLK;
        if (bb == 0) {                      // head fold: Wc = W2@Wl, bc = b2@Wl+bl
            for (int t = tid; t < HIDDEN * N_CLASSES + N_CLASSES; t += SCT) {
                if (t < HIDDEN * N_CLASSES) {
                    int k = t / N_CLASSES, c = t % N_CLASSES;
                    float acc = 0.0f;
#pragma unroll
                    for (int j = 0; j < HIDDEN; j++)
                        acc = fmaf(W2[k * HIDDEN + j], Wl[j * N_CLASSES + c], acc);
                    Wc[t] = acc;
                } else {
                    int c = t - HIDDEN * N_CLASSES;
                    float acc = bl[c];
#pragma unroll
                    for (int j = 0; j < HIDDEN; j++)
                        acc = fmaf(b2[j], Wl[j * N_CLASSES + c], acc);
                    bc[c] = acc;
                }
            }
            return;
        }
        int n = (bb - 1) * SCT + tid;       // gstart from sorted batch
        if (n >= N_NODES) return;
        if (n == 0) {
            for (int g = 0; g <= batch[0]; g++) gstart[g] = 0;
        } else {
            int b0 = batch[n - 1], b1 = batch[n];
            for (int g = b0 + 1; g <= b1; g++) gstart[g] = n;
        }
        if (n == N_NODES - 1) {
            for (int g = batch[n] + 1; g <= N_GRAPHS; g++) gstart[g] = N_NODES;
        }
        return;
    }
    // scatter blocks
    __shared__ int pk[ECHUNK];
    __shared__ unsigned short bkl[ECHUNK];
    __shared__ int spk[ECHUNK];             // bucket-sorted pk
    __shared__ unsigned short sbk[ECHUNK];  // bucket id of sorted slot
    __shared__ int h[N_BKT];                // per-bucket count
    __shared__ int lsc[N_BKT];              // inclusive local scan
    __shared__ int gb[N_BKT];               // claimed global base
    __shared__ int cur[N_BKT];              // local running cursor
    for (int i = tid; i < N_BKT; i += SCT) h[i] = 0;
    __syncthreads();
    int e0 = b * ECHUNK;                    // even (ECHUNK even) -> int2 aligned
    int m = min(ECHUNK, N_EDGES - e0);
    if (m < 0) m = 0;
    // hist pass: 2 edges per thread via int2 (N_EDGES and ECHUNK even -> m even)
    for (int i = tid * 2; i < m; i += 2 * SCT) {
        int2 s2 = *(const int2*)(src + e0 + i);
        int2 d2 = *(const int2*)(dst + e0 + i);
        int bk0 = d2.x >> BKT_SHIFT;
        int bk1 = d2.y >> BKT_SHIFT;
        pk[i]     = (s2.x << BKT_SHIFT) | (d2.x & (BKT_NODES - 1));
        pk[i + 1] = (s2.y << BKT_SHIFT) | (d2.y & (BKT_NODES - 1));
        bkl[i]     = (unsigned short)bk0;
        bkl[i + 1] = (unsigned short)bk1;
        atomicAdd(&h[bk0], 1);
        atomicAdd(&h[bk1], 1);
    }
    __syncthreads();
    if (tid < N_BKT) lsc[tid] = h[tid];     // N_BKT=391 < SCT
    __syncthreads();
    for (int off = 1; off < N_BKT; off <<= 1) {   // Hillis-Steele inclusive
        int t = 0;
        if (tid < N_BKT && tid >= off) t = lsc[tid - off];
        __syncthreads();
        if (tid < N_BKT) lsc[tid] += t;
        __syncthreads();
    }
    if (tid < N_BKT) {
        gb[tid] = atomicAdd(&gcur[tid], h[tid]);  // claim this block's runs
        cur[tid] = lsc[tid] - h[tid];             // local exclusive base
    }
    __syncthreads();
    for (int i = tid; i < m; i += SCT) {          // LDS counting-sort reorder
        int bk = bkl[i];
        int p = atomicAdd(&cur[bk], 1);
        spk[p] = pk[i];
        sbk[p] = (unsigned short)bk;
    }
    __syncthreads();
    for (int i = tid; i < m; i += SCT) {          // bucket-contiguous write-out
        int bk = sbk[i];
        int gpos = gb[bk] + (i - (lsc[bk] - h[bk]));
        if (gpos < CAP)                            // defensive (P~0 overflow)
            ebuf[bk * CAP + gpos] = spk[i];
    }
}

// k_bktfill: per-bucket CSR build, single global pass (R8 LDS-sorted write-out).
// ROUND-9: rowptr+deg packed into one word rpd = (rowptr<<8)|min(deg,255) —
// one gather instead of two in both consumer kernels. (deg is ~Poisson(12.5);
// P(deg>255) ~ 0, min() keeps it safe.)
__global__ void k_bktfill(const int* __restrict__ ebuf, const int* __restrict__ gcur,
                          const float* __restrict__ x,
                          int* __restrict__ rpd,
                          float* __restrict__ dis, uint2* __restrict__ xs4,
                          int* __restrict__ elist) {
    __shared__ int eb_l[CAP];
    __shared__ int sorted_l[CAP];
    __shared__ int cnt_l[BKT_NODES];
    __shared__ int cur_l[BKT_NODES];
    __shared__ int ps[BKT_NODES];
    int b = blockIdx.x, tid = threadIdx.x;   // 0..1023
    int n0 = b * BKT_NODES;
    int e0 = b * CAP;
    int cnt = min(gcur[b], CAP);
    if (tid < BKT_NODES) cnt_l[tid] = 0;
    __syncthreads();
    for (int i = tid; i < cnt; i += 1024) {
        int pe = ebuf[e0 + i];
        eb_l[i] = pe;
        atomicAdd(&cnt_l[pe & (BKT_NODES - 1)], 1);
    }
    __syncthreads();
    if (tid < BKT_NODES) ps[tid] = cnt_l[tid];
    __syncthreads();
    for (int off = 1; off < BKT_NODES; off <<= 1) {
        int t = 0;
        if (tid < BKT_NODES && tid >= off) t = ps[tid - off];
        __syncthreads();
        if (tid < BKT_NODES) ps[tid] += t;
        __syncthreads();
    }
    if (tid < BKT_NODES) {
        int node = n0 + tid;
        int excl = ps[tid] - cnt_l[tid];       // exclusive scan
        cur_l[tid] = excl;
        if (node < N_NODES) {
            int dgc = cnt_l[tid];
            rpd[node] = ((e0 + excl) << 8) | min(dgc, 255);
            float dv = rsqrtf((float)dgc + 1.0f);
            dis[node] = dv;
            float x0 = x[node * 3 + 0], x1 = x[node * 3 + 1], x2 = x[node * 3 + 2];
            xs4[node] = make_uint2((unsigned)f2bf(x0 * dv) |
                                   ((unsigned)f2bf(x1 * dv) << 16),
                                   (unsigned)f2bf(x2 * dv));
        }
    }
    __syncthreads();
    for (int i = tid; i < cnt; i += 1024) {    // scatter in LDS (node order)
        int pe = eb_l[i];
        int pos = atomicAdd(&cur_l[pe & (BKT_NODES - 1)], 1);
        sorted_l[pos] = ((unsigned)pe) >> BKT_SHIFT;
    }
    __syncthreads();
    for (int i = tid; i < cnt; i += 1024)      // coalesced copy-out
        elist[e0 + i] = sorted_l[i];
}

// ---------------------------------------------------------------------------
// fused layer-1: FOUR nodes per wave (16 lanes each), 2 gathers in flight per
// lane (R7-proven), bf16 row output (128B/node, dis pre-multiplied).
__global__ void k_l1fused(const int* __restrict__ rpdA,
                          const int* __restrict__ elist,
                          const float* __restrict__ dis, const uint2* __restrict__ xs4,
                          const float* __restrict__ W1, const float* __restrict__ b1,
                          unsigned* __restrict__ h1b) {
    int w = threadIdx.x >> 6, lane = threadIdx.x & 63;
    int q4 = lane >> 4;                   // which of 4 nodes in this wave
    int j  = lane & 15;                   // lane within node (16-wide)
    int node = blockIdx.x * 16 + w * 4 + q4;   // 6250*16 = 100000 exact
    int rv = rpdA[node];
    int start = ((unsigned)rv) >> 8;
    int dg = rv & 255;
    float a0 = 0.f, a1 = 0.f, a2 = 0.f;
    for (int k = 0; k < dg; k += 32) {    // 2 gathers in flight per lane
        int ia = k + j, ib = k + 16 + j;
        bool aa = ia < dg, ab = ib < dg;
        int sa = elist[start + (aa ? ia : 0)];
        int sb = elist[start + (ab ? ib : 0)];
        uint2 ua = xs4[sa];
        uint2 ub = xs4[sb];
        float ma = aa ? 1.0f : 0.0f;
        float mb = ab ? 1.0f : 0.0f;
        a0 = fmaf(__uint_as_float(ua.x << 16), ma, a0);
        a1 = fmaf(__uint_as_float(ua.x & 0xFFFF0000u), ma, a1);
        a2 = fmaf(__uint_as_float(ua.y << 16), ma, a2);
        a0 = fmaf(__uint_as_float(ub.x << 16), mb, a0);
        a1 = fmaf(__uint_as_float(ub.x & 0xFFFF0000u), mb, a1);
        a2 = fmaf(__uint_as_float(ub.y << 16), mb, a2);
    }
#pragma unroll
    for (int off = 1; off < 16; off <<= 1) {   // butterfly within 16-lane quarter
        a0 += __shfl_xor(a0, off);
        a1 += __shfl_xor(a1, off);
        a2 += __shfl_xor(a2, off);
    }
    uint2 un = xs4[node];
    float dn = dis[node];
    a0 = dn * (a0 + __uint_as_float(un.x << 16));
    a1 = dn * (a1 + __uint_as_float(un.x & 0xFFFF0000u));
    a2 = dn * (a2 + __uint_as_float(un.y << 16));
    // each lane: channels 4j .. 4j+3; row element = relu(h1)*dis_node in bf16
    float v[4];
#pragma unroll
    for (int i = 0; i < 4; i++) {
        int c = 4 * j + i;
        float t = a0 * W1[c] + a1 * W1[HIDDEN + c] + a2 * W1[2 * HIDDEN + c] + b1[c];
        v[i] = fmaxf(t, 0.0f) * dn;
    }
    unsigned w0 = (unsigned)f2bf(v[0]) | ((unsigned)f2bf(v[1]) << 16);
    unsigned w1 = (unsigned)f2bf(v[2]) | ((unsigned)f2bf(v[3]) << 16);
    // row = 32 dwords; lane j owns dwords 2j,2j+1 -> 128B coalesced per node
    *(uint2*)(h1b + (size_t)node * 32 + j * 2) = make_uint2(w0, w1);
}

// ---------------------------------------------------------------------------
// fused 64-channel gather + mean-pool accumulate (2 nodes/wave, bf16 rows,
// R8-proven 4-edges-in-flight unroll).
__global__ void k_gatherpool(const int* __restrict__ rpdA,
                             const int* __restrict__ elist,
                             const float* __restrict__ dis,
                             const unsigned* __restrict__ h1b,
                             const int* __restrict__ batch,
                             float* __restrict__ gsum8) {
    __shared__ float acc_s[8][HIDDEN];
    __shared__ int gid[8];
    int w = threadIdx.x >> 6, lane = threadIdx.x & 63;
    int half = lane >> 5;                       // which of 2 nodes in this wave
    int l32 = lane & 31;
    int node = blockIdx.x * 8 + w * 2 + half;   // 12500*8 = 100000 exact
    int rv = rpdA[node];
    int start = ((unsigned)rv) >> 8;
    int dg = rv & 255;
    int eg = l32 >> 3;       // which of 4 concurrent edges
    int ch = lane & 7;       // which 16B slice (8 channels) of the 128B row
    float acc[8] = {0.f, 0.f, 0.f, 0.f, 0.f, 0.f, 0.f, 0.f};
    for (int k = 0; k < dg; k += 16) {    // 4 edges sequential per lane group
        int i0 = k + eg, i1 = k + 4 + eg, i2 = k + 8 + eg, i3 = k + 12 + eg;
        bool a0b = i0 < dg, a1b = i1 < dg, a2b = i2 < dg, a3b = i3 < dg;
        int s0 = elist[start + (a0b ? i0 : 0)];
        int s1 = elist[start + (a1b ? i1 : 0)];
        int s2 = elist[start + (a2b ? i2 : 0)];
        int s3 = elist[start + (a3b ? i3 : 0)];
        float m0 = a0b ? 1.0f : 0.0f;
        float m1 = a1b ? 1.0f : 0.0f;
        float m2 = a2b ? 1.0f : 0.0f;
        float m3 = a3b ? 1.0f : 0.0f;
        uint4 u0 = *(const uint4*)(h1b + (size_t)s0 * 32 + ch * 4);
        uint4 u1 = *(const uint4*)(h1b + (size_t)s1 * 32 + ch * 4);
        uint4 u2 = *(const uint4*)(h1b + (size_t)s2 * 32 + ch * 4);
        uint4 u3 = *(const uint4*)(h1b + (size_t)s3 * 32 + ch * 4);
        acc[0] = fmaf(__uint_as_float(u0.x << 16),          m0, acc[0]);
        acc[1] = fmaf(__uint_as_float(u0.x & 0xFFFF0000u),  m0, acc[1]);
        acc[2] = fmaf(__uint_as_float(u0.y << 16),          m0, acc[2]);
        acc[3] = fmaf(__uint_as_float(u0.y & 0xFFFF0000u),  m0, acc[3]);
        acc[4] = fmaf(__uint_as_float(u0.z << 16),          m0, acc[4]);
        acc[5] = fmaf(__uint_as_float(u0.z & 0xFFFF0000u),  m0, acc[5]);
        acc[6] = fmaf(__uint_as_float(u0.w << 16),          m0, acc[6]);
        acc[7] = fmaf(__uint_as_float(u0.w & 0xFFFF0000u),  m0, acc[7]);
        acc[0] = fmaf(__uint_as_float(u1.x << 16),          m1, acc[0]);
        acc[1] = fmaf(__uint_as_float(u1.x & 0xFFFF0000u),  m1, acc[1]);
        acc[2] = fmaf(__uint_as_float(u1.y << 16),          m1, acc[2]);
        acc[3] = fmaf(__uint_as_float(u1.y & 0xFFFF0000u),  m1, acc[3]);
        acc[4] = fmaf(__uint_as_float(u1.z << 16),          m1, acc[4]);
        acc[5] = fmaf(__uint_as_float(u1.z & 0xFFFF0000u),  m1, acc[5]);
        acc[6] = fmaf(__uint_as_float(u1.w << 16),          m1, acc[6]);
        acc[7] = fmaf(__uint_as_float(u1.w & 0xFFFF0000u),  m1, acc[7]);
        acc[0] = fmaf(__uint_as_float(u2.x << 16),          m2, acc[0]);
        acc[1] = fmaf(__uint_as_float(u2.x & 0xFFFF0000u),  m2, acc[1]);
        acc[2] = fmaf(__uint_as_float(u2.y << 16),          m2, acc[2]);
        acc[3] = fmaf(__uint_as_float(u2.y & 0xFFFF0000u),  m2, acc[3]);
        acc[4] = fmaf(__uint_as_float(u2.z << 16),          m2, acc[4]);
        acc[5] = fmaf(__uint_as_float(u2.z & 0xFFFF0000u),  m2, acc[5]);
        acc[6] = fmaf(__uint_as_float(u2.w << 16),          m2, acc[6]);
        acc[7] = fmaf(__uint_as_float(u2.w & 0xFFFF0000u),  m2, acc[7]);
        acc[0] = fmaf(__uint_as_float(u3.x << 16),          m3, acc[0]);
        acc[1] = fmaf(__uint_as_float(u3.x & 0xFFFF0000u),  m3, acc[1]);
        acc[2] = fmaf(__uint_as_float(u3.y << 16),          m3, acc[2]);
        acc[3] = fmaf(__uint_as_float(u3.y & 0xFFFF0000u),  m3, acc[3]);
        acc[4] = fmaf(__uint_as_float(u3.z << 16),          m3, acc[4]);
        acc[5] = fmaf(__uint_as_float(u3.z & 0xFFFF0000u),  m3, acc[5]);
        acc[6] = fmaf(__uint_as_float(u3.w << 16),          m3, acc[6]);
        acc[7] = fmaf(__uint_as_float(u3.w & 0xFFFF0000u),  m3, acc[7]);
    }
#pragma unroll
    for (int i = 0; i < 8; i++) {         // reduce 4 edge-groups (within half)
        acc[i] += __shfl_xor(acc[i], 8);
        acc[i] += __shfl_xor(acc[i], 16);
    }
    if (l32 == 0) gid[w * 2 + half] = batch[node];
    if (l32 < 8) {                        // eg==0 lanes hold slice l32
        float dn = dis[node];
        uint4 u = *(const uint4*)(h1b + (size_t)node * 32 + l32 * 4);
        float o[8];
        o[0] = dn * (acc[0] + __uint_as_float(u.x << 16));
        o[1] = dn * (acc[1] + __uint_as_float(u.x & 0xFFFF0000u));
        o[2] = dn * (acc[2] + __uint_as_float(u.y << 16));
        o[3] = dn * (acc[3] + __uint_as_float(u.y & 0xFFFF0000u));
        o[4] = dn * (acc[4] + __uint_as_float(u.z << 16));
        o[5] = dn * (acc[5] + __uint_as_float(u.z & 0xFFFF0000u));
        o[6] = dn * (acc[6] + __uint_as_float(u.w << 16));
        o[7] = dn * (acc[7] + __uint_as_float(u.w & 0xFFFF0000u));
        float* dst = &acc_s[w * 2 + half][l32 * 8];
        *(float4*)(dst)     = make_float4(o[0], o[1], o[2], o[3]);
        *(float4*)(dst + 4) = make_float4(o[4], o[5], o[6], o[7]);
    }
    __syncthreads();
    float* gs = gsum8 + (size_t)(blockIdx.x & (NREP - 1)) * (N_GRAPHS * HIDDEN);
    if (threadIdx.x < HIDDEN) {
        int t = threadIdx.x;
#pragma unroll
        for (int wv = 0; wv < 8; wv++) {
            int gw = gid[wv];
            bool first = true;
#pragma unroll
            for (int u = 0; u < wv; u++)
                if (gid[u] == gw) first = false;
            if (first) {
                float s = acc_s[wv][t];
#pragma unroll
                for (int u2 = wv + 1; u2 < 8; u2++)
                    if (gid[u2] == gw) s += acc_s[u2][t];
                atomicAdd(&gs[gw * HIDDEN + t], s);
            }
        }
    }
}

// head: one block (64 thr) per graph; sum the NREP gsum replicas, then
// out[g,c] = (gl @ Wc[:,c]) / max(cnt,1) + bc[c]
__global__ void k_head(const float* __restrict__ gsum8, const int* __restrict__ gstart,
                       const float* __restrict__ Wc, const float* __restrict__ bc,
                       float* __restrict__ out) {
    __shared__ float gl[HIDDEN];
    int g = blockIdx.x, t = threadIdx.x;
    float s = 0.0f;
#pragma unroll
    for (int r = 0; r < NREP; r++)
        s += gsum8[(size_t)r * (N_GRAPHS * HIDDEN) + g * HIDDEN + t];
    gl[t] = s;
    __syncthreads();
    if (t < N_CLASSES) {
        float cntf = fmaxf((float)(gstart[g + 1] - gstart[g]), 1.0f);
        float dot = 0.0f;
#pragma unroll
        for (int k = 0; k < HIDDEN; k++)
            dot = fmaf(gl[k], Wc[k * N_CLASSES + t], dot);
        out[g * N_CLASSES + t] = dot / cntf + bc[t];
    }
}

// ---------------------------------------------------------------------------
extern "C" void kernel_launch(void* const* d_in, const int* in_sizes, int n_in,
                              void* d_out, int out_size, void* d_ws, size_t ws_size,
                              hipStream_t stream) {
    const float* x     = (const float*)d_in[0];
    const int*   ei    = (const int*)  d_in[1];   // [2, N_EDGES] flat: src then dst
    const int*   batch = (const int*)  d_in[2];
    const float* W1    = (const float*)d_in[3];
    const float* b1    = (const float*)d_in[4];
    const float* W2    = (const float*)d_in[5];
    const float* b2    = (const float*)d_in[6];
    const float* Wl    = (const float*)d_in[7];
    const float* bl    = (const float*)d_in[8];
    float* out = (float*)d_out;

    const int* src = ei;
    const int* dst = ei + N_EDGES;

    // workspace layout (4B words; gcur+gsum8 adjacent so ONE memset zeros both;
    // even word offsets keep xs4 8B- and h1b 16B-aligned)
    int*   gcur    = (int*)d_ws;                         // 391, pad to 512
    float* gsum8   = (float*)(gcur + 512);               // NREP*512*64
    int*   ebuf    = (int*)(gsum8 + NREP * N_GRAPHS * HIDDEN); // N_BKT*CAP
    int*   elist   = ebuf + N_BKT * CAP;                 // N_BKT*CAP
    int*   rpd     = elist + N_BKT * CAP;                // N (packed rp|deg)
    float* dis     = (float*)(rpd + N_NODES);            // N
    uint2* xs4     = (uint2*)(dis + N_NODES);            // N uint2 (8B-aligned)
    unsigned* h1b  = (unsigned*)(xs4 + N_NODES);         // 32N words (bf16 rows)
    int*   gstart  = (int*)(h1b + (size_t)N_NODES * 32); // N_GRAPHS+1 (pad 516)
    float* Wc      = (float*)(gstart + 516);             // 64*5
    float* bc      = Wc + HIDDEN * N_CLASSES;            // 5

    const int BS = 256;
    const int g_nodes_sct = (N_NODES + SCT - 1) / SCT;   // 196 gstart blocks

    // zero gcur + all gsum replicas in one memset, then merged scatter kernel
    hipMemsetAsync(gcur, 0, (512 + NREP * N_GRAPHS * HIDDEN) * sizeof(int), stream);
    k_scat<<<EBLK + 1 + g_nodes_sct, SCT, 0, stream>>>(src, dst, W2, Wl, b2, bl, batch,
                                                       gcur, ebuf, Wc, bc, gstart);
    k_bktfill<<<N_BKT, 1024, 0, stream>>>(ebuf, gcur, x, rpd, dis, xs4, elist);

    // fused layer 1 (4 nodes/wave; 2 gathers in flight per lane)
    k_l1fused<<<N_NODES / 16, BS, 0, stream>>>(rpd, elist, dis, xs4, W1, b1, h1b);

    // layer 2 aggregation fused with mean-pool accumulation (2 nodes/wave,
    // 4 row loads in flight per lane)
    k_gatherpool<<<N_NODES / 8, BS, 0, stream>>>(rpd, elist, dis, h1b,
                                                 batch, gsum8);

    // folded head (block per graph; sums the NREP replicas)
    k_head<<<N_GRAPHS, HIDDEN, 0, stream>>>(gsum8, gstart, Wc, bc, out);
}

// Round 11
// 142.718 us; speedup vs baseline: 1.0563x; 1.0563x over previous
//
#include <hip/hip_runtime.h>
#include <hip/hip_bf16.h>

#define N_NODES   100000
#define N_EDGES   1250000
#define N_GRAPHS  512
#define HIDDEN    64
#define F_IN      3
#define N_CLASSES 5

// bucket sort parameters
#define BKT_SHIFT 8
#define BKT_NODES 256                                      // nodes per bucket
#define N_BKT     ((N_NODES + BKT_NODES - 1) / BKT_NODES)  // 391
#define CAP       4096                                     // fixed bucket capacity
// ROUND-11: EBLK back to 512 (R10 showed 1024 blocks doubles per-block scan/
// claim fixed costs: +7us). Occupancy instead comes from SCT 512 -> 1024:
// same 512 blocks, 16 waves each, 35.5KB LDS -> 2 blocks/CU = 2048 thr/CU
// (full), with the SAME number of scan instances as R8.
#define EBLK      512
#define ECHUNK    ((((N_EDGES + EBLK - 1) / EBLK) + 1) & ~1)   // 2442 (even)
#define SCT       1024                                     // k_scat threads
#define NREP      8                                        // gsum replicas

// bf16 helpers (RNE; inputs are finite)
__device__ __forceinline__ unsigned short f2bf(float f) {
    unsigned u = __float_as_uint(f);
    u += 0x7FFF + ((u >> 16) & 1);
    return (unsigned short)(u >> 16);
}

// ---------------------------------------------------------------------------
// k_scat: merged hist + scan + bucket-base claim + LDS counting-sort reorder
// + bucket-contiguous write-out (+ head fold, gstart in extra blocks).
// R8-proven structure; int2 edge reads (R9), 1024 threads/block (R11).
__global__ void __launch_bounds__(SCT) k_scat(
        const int* __restrict__ src, const int* __restrict__ dst,
        const float* __restrict__ W2, const float* __restrict__ Wl,
        const float* __restrict__ b2, const float* __restrict__ bl,
        const int* __restrict__ batch,
        int* __restrict__ gcur, int* __restrict__ ebuf,
        float* __restrict__ Wc, float* __restrict__ bc,
        int* __restrict__ gstart) {
    int b = blockIdx.x;
    int tid = threadIdx.x;
    if (b >= EBLK) {
        int bb = b - EBLK;
        if (bb == 0) {                      // head fold: Wc = W2@Wl, bc = b2@Wl+bl
            for (int t = tid; t < HIDDEN * N_CLASSES + N_CLASSES; t += SCT) {
                if (t < HIDDEN * N_CLASSES) {
                    int k = t / N_CLASSES, c = t % N_CLASSES;
                    float acc = 0.0f;
#pragma unroll
                    for (int j = 0; j < HIDDEN; j++)
                        acc = fmaf(W2[k * HIDDEN + j], Wl[j * N_CLASSES + c], acc);
                    Wc[t] = acc;
                } else {
                    int c = t - HIDDEN * N_CLASSES;
                    float acc = bl[c];
#pragma unroll
                    for (int j = 0; j < HIDDEN; j++)
                        acc = fmaf(b2[j], Wl[j * N_CLASSES + c], acc);
                    bc[c] = acc;
                }
            }
            return;
        }
        int n = (bb - 1) * SCT + tid;       // gstart from sorted batch
        if (n >= N_NODES) return;
        if (n == 0) {
            for (int g = 0; g <= batch[0]; g++) gstart[g] = 0;
        } else {
            int b0 = batch[n - 1], b1 = batch[n];
            for (int g = b0 + 1; g <= b1; g++) gstart[g] = n;
        }
        if (n == N_NODES - 1) {
            for (int g = batch[n] + 1; g <= N_GRAPHS; g++) gstart[g] = N_NODES;
        }
        return;
    }
    // scatter blocks
    __shared__ int pk[ECHUNK];
    __shared__ unsigned short bkl[ECHUNK];
    __shared__ int spk[ECHUNK];             // bucket-sorted pk
    __shared__ unsigned short sbk[ECHUNK];  // bucket id of sorted slot
    __shared__ int h[N_BKT];                // per-bucket count
    __shared__ int lsc[N_BKT];              // inclusive local scan
    __shared__ int gb[N_BKT];               // claimed global base
    __shared__ int cur[N_BKT];              // local running cursor
    for (int i = tid; i < N_BKT; i += SCT) h[i] = 0;
    __syncthreads();
    int e0 = b * ECHUNK;                    // even (ECHUNK even) -> int2 aligned
    int m = min(ECHUNK, N_EDGES - e0);
    if (m < 0) m = 0;
    // hist pass: 2 edges per thread via int2 (N_EDGES and ECHUNK even -> m even)
    for (int i = tid * 2; i < m; i += 2 * SCT) {
        int2 s2 = *(const int2*)(src + e0 + i);
        int2 d2 = *(const int2*)(dst + e0 + i);
        int bk0 = d2.x >> BKT_SHIFT;
        int bk1 = d2.y >> BKT_SHIFT;
        pk[i]     = (s2.x << BKT_SHIFT) | (d2.x & (BKT_NODES - 1));
        pk[i + 1] = (s2.y << BKT_SHIFT) | (d2.y & (BKT_NODES - 1));
        bkl[i]     = (unsigned short)bk0;
        bkl[i + 1] = (unsigned short)bk1;
        atomicAdd(&h[bk0], 1);
        atomicAdd(&h[bk1], 1);
    }
    __syncthreads();
    if (tid < N_BKT) lsc[tid] = h[tid];     // N_BKT=391 < SCT
    __syncthreads();
    for (int off = 1; off < N_BKT; off <<= 1) {   // Hillis-Steele inclusive
        int t = 0;
        if (tid < N_BKT && tid >= off) t = lsc[tid - off];
        __syncthreads();
        if (tid < N_BKT) lsc[tid] += t;
        __syncthreads();
    }
    if (tid < N_BKT) {
        gb[tid] = atomicAdd(&gcur[tid], h[tid]);  // claim this block's runs
        cur[tid] = lsc[tid] - h[tid];             // local exclusive base
    }
    __syncthreads();
    for (int i = tid; i < m; i += SCT) {          // LDS counting-sort reorder
        int bk = bkl[i];
        int p = atomicAdd(&cur[bk], 1);
        spk[p] = pk[i];
        sbk[p] = (unsigned short)bk;
    }
    __syncthreads();
    for (int i = tid; i < m; i += SCT) {          // bucket-contiguous write-out
        int bk = sbk[i];
        int gpos = gb[bk] + (i - (lsc[bk] - h[bk]));
        if (gpos < CAP)                            // defensive (P~0 overflow)
            ebuf[bk * CAP + gpos] = spk[i];
    }
}

// k_bktfill: per-bucket CSR build, single global pass (R8 LDS-sorted write-out,
// R9 rpd = (rowptr<<8)|min(deg,255) packing).
__global__ void k_bktfill(const int* __restrict__ ebuf, const int* __restrict__ gcur,
                          const float* __restrict__ x,
                          int* __restrict__ rpd,
                          float* __restrict__ dis, uint2* __restrict__ xs4,
                          int* __restrict__ elist) {
    __shared__ int eb_l[CAP];
    __shared__ int sorted_l[CAP];
    __shared__ int cnt_l[BKT_NODES];
    __shared__ int cur_l[BKT_NODES];
    __shared__ int ps[BKT_NODES];
    int b = blockIdx.x, tid = threadIdx.x;   // 0..1023
    int n0 = b * BKT_NODES;
    int e0 = b * CAP;
    int cnt = min(gcur[b], CAP);
    if (tid < BKT_NODES) cnt_l[tid] = 0;
    __syncthreads();
    for (int i = tid; i < cnt; i += 1024) {
        int pe = ebuf[e0 + i];
        eb_l[i] = pe;
        atomicAdd(&cnt_l[pe & (BKT_NODES - 1)], 1);
    }
    __syncthreads();
    if (tid < BKT_NODES) ps[tid] = cnt_l[tid];
    __syncthreads();
    for (int off = 1; off < BKT_NODES; off <<= 1) {
        int t = 0;
        if (tid < BKT_NODES && tid >= off) t = ps[tid - off];
        __syncthreads();
        if (tid < BKT_NODES) ps[tid] += t;
        __syncthreads();
    }
    if (tid < BKT_NODES) {
        int node = n0 + tid;
        int excl = ps[tid] - cnt_l[tid];       // exclusive scan
        cur_l[tid] = excl;
        if (node < N_NODES) {
            int dgc = cnt_l[tid];
            rpd[node] = ((e0 + excl) << 8) | min(dgc, 255);
            float dv = rsqrtf((float)dgc + 1.0f);
            dis[node] = dv;
            float x0 = x[node * 3 + 0], x1 = x[node * 3 + 1], x2 = x[node * 3 + 2];
            xs4[node] = make_uint2((unsigned)f2bf(x0 * dv) |
                                   ((unsigned)f2bf(x1 * dv) << 16),
                                   (unsigned)f2bf(x2 * dv));
        }
    }
    __syncthreads();
    for (int i = tid; i < cnt; i += 1024) {    // scatter in LDS (node order)
        int pe = eb_l[i];
        int pos = atomicAdd(&cur_l[pe & (BKT_NODES - 1)], 1);
        sorted_l[pos] = ((unsigned)pe) >> BKT_SHIFT;
    }
    __syncthreads();
    for (int i = tid; i < cnt; i += 1024)      // coalesced copy-out
        elist[e0 + i] = sorted_l[i];
}

// ---------------------------------------------------------------------------
// fused layer-1: FOUR nodes per wave (16 lanes each), 2 gathers in flight per
// lane (R7-proven), bf16 row output (128B/node, dis pre-multiplied).
__global__ void k_l1fused(const int* __restrict__ rpdA,
                          const int* __restrict__ elist,
                          const float* __restrict__ dis, const uint2* __restrict__ xs4,
                          const float* __restrict__ W1, const float* __restrict__ b1,
                          unsigned* __restrict__ h1b) {
    int w = threadIdx.x >> 6, lane = threadIdx.x & 63;
    int q4 = lane >> 4;                   // which of 4 nodes in this wave
    int j  = lane & 15;                   // lane within node (16-wide)
    int node = blockIdx.x * 16 + w * 4 + q4;   // 6250*16 = 100000 exact
    int rv = rpdA[node];
    int start = ((unsigned)rv) >> 8;
    int dg = rv & 255;
    float a0 = 0.f, a1 = 0.f, a2 = 0.f;
    for (int k = 0; k < dg; k += 32) {    // 2 gathers in flight per lane
        int ia = k + j, ib = k + 16 + j;
        bool aa = ia < dg, ab = ib < dg;
        int sa = elist[start + (aa ? ia : 0)];
        int sb = elist[start + (ab ? ib : 0)];
        uint2 ua = xs4[sa];
        uint2 ub = xs4[sb];
        float ma = aa ? 1.0f : 0.0f;
        float mb = ab ? 1.0f : 0.0f;
        a0 = fmaf(__uint_as_float(ua.x << 16), ma, a0);
        a1 = fmaf(__uint_as_float(ua.x & 0xFFFF0000u), ma, a1);
        a2 = fmaf(__uint_as_float(ua.y << 16), ma, a2);
        a0 = fmaf(__uint_as_float(ub.x << 16), mb, a0);
        a1 = fmaf(__uint_as_float(ub.x & 0xFFFF0000u), mb, a1);
        a2 = fmaf(__uint_as_float(ub.y << 16), mb, a2);
    }
#pragma unroll
    for (int off = 1; off < 16; off <<= 1) {   // butterfly within 16-lane quarter
        a0 += __shfl_xor(a0, off);
        a1 += __shfl_xor(a1, off);
        a2 += __shfl_xor(a2, off);
    }
    uint2 un = xs4[node];
    float dn = dis[node];
    a0 = dn * (a0 + __uint_as_float(un.x << 16));
    a1 = dn * (a1 + __uint_as_float(un.x & 0xFFFF0000u));
    a2 = dn * (a2 + __uint_as_float(un.y << 16));
    // each lane: channels 4j .. 4j+3; row element = relu(h1)*dis_node in bf16
    float v[4];
#pragma unroll
    for (int i = 0; i < 4; i++) {
        int c = 4 * j + i;
        float t = a0 * W1[c] + a1 * W1[HIDDEN + c] + a2 * W1[2 * HIDDEN + c] + b1[c];
        v[i] = fmaxf(t, 0.0f) * dn;
    }
    unsigned w0 = (unsigned)f2bf(v[0]) | ((unsigned)f2bf(v[1]) << 16);
    unsigned w1 = (unsigned)f2bf(v[2]) | ((unsigned)f2bf(v[3]) << 16);
    // row = 32 dwords; lane j owns dwords 2j,2j+1 -> 128B coalesced per node
    *(uint2*)(h1b + (size_t)node * 32 + j * 2) = make_uint2(w0, w1);
}

// ---------------------------------------------------------------------------
// fused 64-channel gather + mean-pool accumulate (2 nodes/wave, bf16 rows,
// R8-proven 4-edges-in-flight unroll).
__global__ void k_gatherpool(const int* __restrict__ rpdA,
                             const int* __restrict__ elist,
                             const float* __restrict__ dis,
                             const unsigned* __restrict__ h1b,
                             const int* __restrict__ batch,
                             float* __restrict__ gsum8) {
    __shared__ float acc_s[8][HIDDEN];
    __shared__ int gid[8];
    int w = threadIdx.x >> 6, lane = threadIdx.x & 63;
    int half = lane >> 5;                       // which of 2 nodes in this wave
    int l32 = lane & 31;
    int node = blockIdx.x * 8 + w * 2 + half;   // 12500*8 = 100000 exact
    int rv = rpdA[node];
    int start = ((unsigned)rv) >> 8;
    int dg = rv & 255;
    int eg = l32 >> 3;       // which of 4 concurrent edges
    int ch = lane & 7;       // which 16B slice (8 channels) of the 128B row
    float acc[8] = {0.f, 0.f, 0.f, 0.f, 0.f, 0.f, 0.f, 0.f};
    for (int k = 0; k < dg; k += 16) {    // 4 edges sequential per lane group
        int i0 = k + eg, i1 = k + 4 + eg, i2 = k + 8 + eg, i3 = k + 12 + eg;
        bool a0b = i0 < dg, a1b = i1 < dg, a2b = i2 < dg, a3b = i3 < dg;
        int s0 = elist[start + (a0b ? i0 : 0)];
        int s1 = elist[start + (a1b ? i1 : 0)];
        int s2 = elist[start + (a2b ? i2 : 0)];
        int s3 = elist[start + (a3b ? i3 : 0)];
        float m0 = a0b ? 1.0f : 0.0f;
        float m1 = a1b ? 1.0f : 0.0f;
        float m2 = a2b ? 1.0f : 0.0f;
        float m3 = a3b ? 1.0f : 0.0f;
        uint4 u0 = *(const uint4*)(h1b + (size_t)s0 * 32 + ch * 4);
        uint4 u1 = *(const uint4*)(h1b + (size_t)s1 * 32 + ch * 4);
        uint4 u2 = *(const uint4*)(h1b + (size_t)s2 * 32 + ch * 4);
        uint4 u3 = *(const uint4*)(h1b + (size_t)s3 * 32 + ch * 4);
        acc[0] = fmaf(__uint_as_float(u0.x << 16),          m0, acc[0]);
        acc[1] = fmaf(__uint_as_float(u0.x & 0xFFFF0000u),  m0, acc[1]);
        acc[2] = fmaf(__uint_as_float(u0.y << 16),          m0, acc[2]);
        acc[3] = fmaf(__uint_as_float(u0.y & 0xFFFF0000u),  m0, acc[3]);
        acc[4] = fmaf(__uint_as_float(u0.z << 16),          m0, acc[4]);
        acc[5] = fmaf(__uint_as_float(u0.z & 0xFFFF0000u),  m0, acc[5]);
        acc[6] = fmaf(__uint_as_float(u0.w << 16),          m0, acc[6]);
        acc[7] = fmaf(__uint_as_float(u0.w & 0xFFFF0000u),  m0, acc[7]);
        acc[0] = fmaf(__uint_as_float(u1.x << 16),          m1, acc[0]);
        acc[1] = fmaf(__uint_as_float(u1.x & 0xFFFF0000u),  m1, acc[1]);
        acc[2] = fmaf(__uint_as_float(u1.y << 16),          m1, acc[2]);
        acc[3] = fmaf(__uint_as_float(u1.y & 0xFFFF0000u),  m1, acc[3]);
        acc[4] = fmaf(__uint_as_float(u1.z << 16),          m1, acc[4]);
        acc[5] = fmaf(__uint_as_float(u1.z & 0xFFFF0000u),  m1, acc[5]);
        acc[6] = fmaf(__uint_as_float(u1.w << 16),          m1, acc[6]);
        acc[7] = fmaf(__uint_as_float(u1.w & 0xFFFF0000u),  m1, acc[7]);
        acc[0] = fmaf(__uint_as_float(u2.x << 16),          m2, acc[0]);
        acc[1] = fmaf(__uint_as_float(u2.x & 0xFFFF0000u),  m2, acc[1]);
        acc[2] = fmaf(__uint_as_float(u2.y << 16),          m2, acc[2]);
        acc[3] = fmaf(__uint_as_float(u2.y & 0xFFFF0000u),  m2, acc[3]);
        acc[4] = fmaf(__uint_as_float(u2.z << 16),          m2, acc[4]);
        acc[5] = fmaf(__uint_as_float(u2.z & 0xFFFF0000u),  m2, acc[5]);
        acc[6] = fmaf(__uint_as_float(u2.w << 16),          m2, acc[6]);
        acc[7] = fmaf(__uint_as_float(u2.w & 0xFFFF0000u),  m2, acc[7]);
        acc[0] = fmaf(__uint_as_float(u3.x << 16),          m3, acc[0]);
        acc[1] = fmaf(__uint_as_float(u3.x & 0xFFFF0000u),  m3, acc[1]);
        acc[2] = fmaf(__uint_as_float(u3.y << 16),          m3, acc[2]);
        acc[3] = fmaf(__uint_as_float(u3.y & 0xFFFF0000u),  m3, acc[3]);
        acc[4] = fmaf(__uint_as_float(u3.z << 16),          m3, acc[4]);
        acc[5] = fmaf(__uint_as_float(u3.z & 0xFFFF0000u),  m3, acc[5]);
        acc[6] = fmaf(__uint_as_float(u3.w << 16),          m3, acc[6]);
        acc[7] = fmaf(__uint_as_float(u3.w & 0xFFFF0000u),  m3, acc[7]);
    }
#pragma unroll
    for (int i = 0; i < 8; i++) {         // reduce 4 edge-groups (within half)
        acc[i] += __shfl_xor(acc[i], 8);
        acc[i] += __shfl_xor(acc[i], 16);
    }
    if (l32 == 0) gid[w * 2 + half] = batch[node];
    if (l32 < 8) {                        // eg==0 lanes hold slice l32
        float dn = dis[node];
        uint4 u = *(const uint4*)(h1b + (size_t)node * 32 + l32 * 4);
        float o[8];
        o[0] = dn * (acc[0] + __uint_as_float(u.x << 16));
        o[1] = dn * (acc[1] + __uint_as_float(u.x & 0xFFFF0000u));
        o[2] = dn * (acc[2] + __uint_as_float(u.y << 16));
        o[3] = dn * (acc[3] + __uint_as_float(u.y & 0xFFFF0000u));
        o[4] = dn * (acc[4] + __uint_as_float(u.z << 16));
        o[5] = dn * (acc[5] + __uint_as_float(u.z & 0xFFFF0000u));
        o[6] = dn * (acc[6] + __uint_as_float(u.w << 16));
        o[7] = dn * (acc[7] + __uint_as_float(u.w & 0xFFFF0000u));
        float* dst = &acc_s[w * 2 + half][l32 * 8];
        *(float4*)(dst)     = make_float4(o[0], o[1], o[2], o[3]);
        *(float4*)(dst + 4) = make_float4(o[4], o[5], o[6], o[7]);
    }
    __syncthreads();
    float* gs = gsum8 + (size_t)(blockIdx.x & (NREP - 1)) * (N_GRAPHS * HIDDEN);
    if (threadIdx.x < HIDDEN) {
        int t = threadIdx.x;
#pragma unroll
        for (int wv = 0; wv < 8; wv++) {
            int gw = gid[wv];
            bool first = true;
#pragma unroll
            for (int u = 0; u < wv; u++)
                if (gid[u] == gw) first = false;
            if (first) {
                float s = acc_s[wv][t];
#pragma unroll
                for (int u2 = wv + 1; u2 < 8; u2++)
                    if (gid[u2] == gw) s += acc_s[u2][t];
                atomicAdd(&gs[gw * HIDDEN + t], s);
            }
        }
    }
}

// head: one block (64 thr) per graph; sum the NREP gsum replicas, then
// out[g,c] = (gl @ Wc[:,c]) / max(cnt,1) + bc[c]
__global__ void k_head(const float* __restrict__ gsum8, const int* __restrict__ gstart,
                       const float* __restrict__ Wc, const float* __restrict__ bc,
                       float* __restrict__ out) {
    __shared__ float gl[HIDDEN];
    int g = blockIdx.x, t = threadIdx.x;
    float s = 0.0f;
#pragma unroll
    for (int r = 0; r < NREP; r++)
        s += gsum8[(size_t)r * (N_GRAPHS * HIDDEN) + g * HIDDEN + t];
    gl[t] = s;
    __syncthreads();
    if (t < N_CLASSES) {
        float cntf = fmaxf((float)(gstart[g + 1] - gstart[g]), 1.0f);
        float dot = 0.0f;
#pragma unroll
        for (int k = 0; k < HIDDEN; k++)
            dot = fmaf(gl[k], Wc[k * N_CLASSES + t], dot);
        out[g * N_CLASSES + t] = dot / cntf + bc[t];
    }
}

// ---------------------------------------------------------------------------
extern "C" void kernel_launch(void* const* d_in, const int* in_sizes, int n_in,
                              void* d_out, int out_size, void* d_ws, size_t ws_size,
                              hipStream_t stream) {
    const float* x     = (const float*)d_in[0];
    const int*   ei    = (const int*)  d_in[1];   // [2, N_EDGES] flat: src then dst
    const int*   batch = (const int*)  d_in[2];
    const float* W1    = (const float*)d_in[3];
    const float* b1    = (const float*)d_in[4];
    const float* W2    = (const float*)d_in[5];
    const float* b2    = (const float*)d_in[6];
    const float* Wl    = (const float*)d_in[7];
    const float* bl    = (const float*)d_in[8];
    float* out = (float*)d_out;

    const int* src = ei;
    const int* dst = ei + N_EDGES;

    // workspace layout (4B words; gcur+gsum8 adjacent so ONE memset zeros both;
    // even word offsets keep xs4 8B- and h1b 16B-aligned)
    int*   gcur    = (int*)d_ws;                         // 391, pad to 512
    float* gsum8   = (float*)(gcur + 512);               // NREP*512*64
    int*   ebuf    = (int*)(gsum8 + NREP * N_GRAPHS * HIDDEN); // N_BKT*CAP
    int*   elist   = ebuf + N_BKT * CAP;                 // N_BKT*CAP
    int*   rpd     = elist + N_BKT * CAP;                // N (packed rp|deg)
    float* dis     = (float*)(rpd + N_NODES);            // N
    uint2* xs4     = (uint2*)(dis + N_NODES);            // N uint2 (8B-aligned)
    unsigned* h1b  = (unsigned*)(xs4 + N_NODES);         // 32N words (bf16 rows)
    int*   gstart  = (int*)(h1b + (size_t)N_NODES * 32); // N_GRAPHS+1 (pad 516)
    float* Wc      = (float*)(gstart + 516);             // 64*5
    float* bc      = Wc + HIDDEN * N_CLASSES;            // 5

    const int BS = 256;
    const int g_nodes_sct = (N_NODES + SCT - 1) / SCT;   // 98 gstart blocks

    // zero gcur + all gsum replicas in one memset, then merged scatter kernel
    hipMemsetAsync(gcur, 0, (512 + NREP * N_GRAPHS * HIDDEN) * sizeof(int), stream);
    k_scat<<<EBLK + 1 + g_nodes_sct, SCT, 0, stream>>>(src, dst, W2, Wl, b2, bl, batch,
                                                       gcur, ebuf, Wc, bc, gstart);
    k_bktfill<<<N_BKT, 1024, 0, stream>>>(ebuf, gcur, x, rpd, dis, xs4, elist);

    // fused layer 1 (4 nodes/wave; 2 gathers in flight per lane)
    k_l1fused<<<N_NODES / 16, BS, 0, stream>>>(rpd, elist, dis, xs4, W1, b1, h1b);

    // layer 2 aggregation fused with mean-pool accumulation (2 nodes/wave,
    // 4 row loads in flight per lane)
    k_gatherpool<<<N_NODES / 8, BS, 0, stream>>>(rpd, elist, dis, h1b,
                                                 batch, gsum8);

    // folded head (block per graph; sums the NREP replicas)
    k_head<<<N_GRAPHS, HIDDEN, 0, stream>>>(gsum8, gstart, Wc, bc, out);
}